// Round 12
// baseline (1153.508 us; speedup 1.0000x reference)
//
#include <hip/hip_runtime.h>
#include <hip/hip_bf16.h>
#include <math.h>

// Problem constants
constexpr int Bb  = 4;
constexpr int SEQ = 2048;
constexpr int Dd  = 1024;
constexpr int Hh  = 16;
constexpr int DHh = 64;
constexpr int Cc  = 64;            // chunk length
constexpr int NCc = SEQ / Cc;      // 32 chunks
constexpr int Mm  = Bb * SEQ;      // 8192 rows
constexpr float EPSf = 1e-6f;

typedef __attribute__((ext_vector_type(8))) short bf16x8;
typedef __attribute__((ext_vector_type(4))) float f32x4;
typedef __attribute__((ext_vector_type(8))) unsigned short u16x8;

__device__ __forceinline__ float bf2f(unsigned short u) {
    return __uint_as_float((unsigned)u << 16);
}
__device__ __forceinline__ unsigned short f2bf(float f) {
    unsigned u = __float_as_uint(f);
    unsigned r = u + 0x7fff + ((u >> 16) & 1);   // RNE
    return (unsigned short)(r >> 16);
}
// XOR swizzle for transposed LDS tiles (chunk kernels)
__device__ __forceinline__ int swz(int row, int col) {
    return col ^ (((row >> 3) & 7) << 3);
}

// ---------------------------------------------------------------------------
// prep: fused {x fp32->bf16 cast} + {W transpose-cast}.
// ---------------------------------------------------------------------------
__global__ __launch_bounds__(256)
void prep(const float* __restrict__ x,
          const float* __restrict__ W0, const float* __restrict__ W1,
          const float* __restrict__ W2, const float* __restrict__ W3,
          unsigned short* __restrict__ xb, unsigned short* __restrict__ WT) {
    __shared__ float t[64][65];
    const int tid = threadIdx.x;
    if (blockIdx.x < 4096) {
        int i = blockIdx.x * 256 + tid;
        const float4* p = reinterpret_cast<const float4*>(x) + (size_t)i * 2;
        float4 a = p[0], b = p[1];
        u16x8 o;
        o[0] = f2bf(a.x); o[1] = f2bf(a.y); o[2] = f2bf(a.z); o[3] = f2bf(a.w);
        o[4] = f2bf(b.x); o[5] = f2bf(b.y); o[6] = f2bf(b.z); o[7] = f2bf(b.w);
        *(reinterpret_cast<u16x8*>(xb) + i) = o;
        return;
    }
    const int tb = blockIdx.x - 4096;
    const int z  = tb >> 8;
    const int by = (tb >> 4) & 15, bx = tb & 15;
    const float* W = (z == 0) ? W0 : (z == 1) ? W1 : (z == 2) ? W2 : W3;
    unsigned short* T = WT + (size_t)z * Dd * Dd;
    const int r0 = by * 64, c0 = bx * 64;
    const int lr = tid >> 4, lc4 = (tid & 15) * 4;
#pragma unroll
    for (int it = 0; it < 4; ++it) {
        int row = lr + it * 16;
        float4 v = *reinterpret_cast<const float4*>(W + (size_t)(r0 + row) * Dd + c0 + lc4);
        t[row][lc4 + 0] = v.x; t[row][lc4 + 1] = v.y;
        t[row][lc4 + 2] = v.z; t[row][lc4 + 3] = v.w;
    }
    __syncthreads();
#pragma unroll
    for (int it = 0; it < 4; ++it) {
        int col = lr + it * 16;
        ushort4 o;
        o.x = f2bf(t[lc4 + 0][col]); o.y = f2bf(t[lc4 + 1][col]);
        o.z = f2bf(t[lc4 + 2][col]); o.w = f2bf(t[lc4 + 3][col]);
        *reinterpret_cast<ushort4*>(T + (size_t)(c0 + col) * Dd + r0 + lc4) = o;
    }
}

// ---------------------------------------------------------------------------
// bf16 MFMA GEMM — 256x256 tile, LDS-traffic-minimal wave geometry:
//   BM=BN=256, BK=64; 512 threads = 8 waves (2M x 4N), wave owns 128x64.
//   LDS-BW model (validated on round-7: 1376cy/tile predicted vs 1600 meas):
//   reads/tile = A 32KB x4-wave-share-per-half + B 32KB x2 = 192KB + 64KB
//   stage = 256KB per 2 tile-equivalents -> 1.38x less LDS traffic per FLOP
//   than 128x256/64x64.  SINGLE-buffered 64KB LDS -> 2 blocks/CU: cross-
//   block overlap (m97/m114 mechanism) covers the per-tile stage drain.
//   m97 2-barrier loop; counted lgkm splits compute into 2x32-MFMA groups
//   (ks0 while ks1 reads in flight).  Swizzle identical to round 7 (0 confl).
//   Epilogue: wave-private 8KB LDS regions, u16x8/float4 stores.
// QKV=1: N=3072 fused (Wq|Wk|Wv), bf16 out, phi on Q,K. QKV=0: N=1024, f32.
// Grid: QKV 384 blocks (all co-resident at 2/CU), out 128.  XCD A-band
// mapping: by = xcd*4 + i/GX (bijective, A-band 2MB L2-resident per XCD).
// ---------------------------------------------------------------------------
template<int QKV>
__global__ __launch_bounds__(512, 4)
void gemm_256s(const unsigned short* __restrict__ A, const unsigned short* __restrict__ BT,
               float* __restrict__ outF, unsigned short* __restrict__ oQ,
               unsigned short* __restrict__ oK, unsigned short* __restrict__ oV) {
    constexpr int Kd = 1024;
    constexpr int BK = 64;
    constexpr int NT = Kd / BK;            // 16 K-tiles
    constexpr int GX = QKV ? 12 : 4;       // N / 256

    __shared__ __align__(16) unsigned short lds[32768];   // 64 KB: A 32KB | B 32KB

    const int wg0 = blockIdx.x;
    const int xcd = wg0 & 7;
    const int i   = wg0 >> 3;
    const int by  = xcd * 4 + i / GX;      // (M/256)/8 = 4 row-blocks per XCD
    const int bx  = i % GX;
    const int row0 = by * 256;
    const int col0 = bx * 256;

    const int tid  = threadIdx.x;
    const int lane = tid & 63;
    const int wave = tid >> 6;             // 0..7
    const int wm = (wave >> 2) * 128;      // wave M offset (0,128)
    const int wn = (wave & 3) * 64;        // wave N offset (0..192)
    const int fr = lane & 15;
    const int hi = lane >> 4;

    f32x4 acc[8][4];
#pragma unroll
    for (int mf = 0; mf < 8; ++mf)
#pragma unroll
        for (int nf = 0; nf < 4; ++nf) acc[mf][nf] = (f32x4){0.f, 0.f, 0.f, 0.f};

    // one 8KB cooperative load; l = 0..3 A-quarters, 4..7 B-quarters
    auto stage1 = [&](int kt, int l) {
        int seg = l * 512 + tid;                      // 0..4095
        if (l < 4) {                                  // A: segs 0..2047
            int row = seg >> 3, sp = seg & 7;
            int gcol = kt + ((sp ^ (row & 7)) << 3);  // inverse-swizzled source
            __builtin_amdgcn_global_load_lds(
                (const __attribute__((address_space(1))) void*)(A + (size_t)(row0 + row) * Kd + gcol),
                (__attribute__((address_space(3))) void*)(lds + seg * 8), 16, 0, 0);
        } else {
            int bseg = seg - 2048;                    // B: segs 0..2047
            int row = bseg >> 3, sp = bseg & 7;
            int gcol = kt + ((sp ^ (row & 7)) << 3);
            __builtin_amdgcn_global_load_lds(
                (const __attribute__((address_space(1))) void*)(BT + (size_t)(col0 + row) * Kd + gcol),
                (__attribute__((address_space(3))) void*)(lds + 16384 + bseg * 8), 16, 0, 0);
        }
    };
    // swizzled fragment reads (row stride 128B; sp^(row&7) -> 2-way = free)
    auto lda = [&](int mf, int ks) {
        int row = wm + mf * 16 + fr;
        int sp = ((ks << 2) | hi) ^ (row & 7);
        return *reinterpret_cast<const bf16x8*>(lds + row * 64 + sp * 8);
    };
    auto ldb = [&](int nf, int ks) {
        int row = wn + nf * 16 + fr;
        int sp = ((ks << 2) | hi) ^ (row & 7);
        return *reinterpret_cast<const bf16x8*>(lds + 16384 + row * 64 + sp * 8);
    };

#define SB0 __builtin_amdgcn_sched_barrier(0);

    // prologue: stage tile 0
#pragma unroll
    for (int l = 0; l < 8; ++l) stage1(0, l);

    for (int t = 0; t < NT; ++t) {
        asm volatile("s_waitcnt vmcnt(0)" ::: "memory");   // tile t landed
        SB0
        __builtin_amdgcn_s_barrier();
        SB0

        bf16x8 a0[8], a1[8], b0[4], b1[4];
#pragma unroll
        for (int mf = 0; mf < 8; ++mf) a0[mf] = lda(mf, 0);
#pragma unroll
        for (int nf = 0; nf < 4; ++nf) b0[nf] = ldb(nf, 0);
#pragma unroll
        for (int mf = 0; mf < 8; ++mf) a1[mf] = lda(mf, 1);
#pragma unroll
        for (int nf = 0; nf < 4; ++nf) b1[nf] = ldb(nf, 1);

        asm volatile("s_waitcnt lgkmcnt(12)" ::: "memory");  // ks0 set ready
        SB0
        __builtin_amdgcn_s_setprio(1);
#pragma unroll
        for (int mf = 0; mf < 8; ++mf)
#pragma unroll
            for (int nf = 0; nf < 4; ++nf)
                acc[mf][nf] = __builtin_amdgcn_mfma_f32_16x16x32_bf16(a0[mf], b0[nf], acc[mf][nf], 0, 0, 0);
        __builtin_amdgcn_s_setprio(0);

        asm volatile("s_waitcnt lgkmcnt(0)" ::: "memory");   // ks1 set ready
        SB0
        __builtin_amdgcn_s_setprio(1);
#pragma unroll
        for (int mf = 0; mf < 8; ++mf)
#pragma unroll
            for (int nf = 0; nf < 4; ++nf)
                acc[mf][nf] = __builtin_amdgcn_mfma_f32_16x16x32_bf16(a1[mf], b1[nf], acc[mf][nf], 0, 0, 0);
        __builtin_amdgcn_s_setprio(0);

        SB0
        __builtin_amdgcn_s_barrier();      // all reads of tile t done
        SB0
        if (t + 1 < NT) {
#pragma unroll
            for (int l = 0; l < 8; ++l) stage1((t + 1) * BK, l);
        }
    }
#undef SB0

    // ---- vectorized epilogue via wave-private 8KB LDS regions ----
    if (QKV) {
        const int sel = col0 >> 10;        // 0=Q,1=K,2=V (256-tiles don't straddle)
        unsigned short* ob = (sel == 0) ? oQ : (sel == 1) ? oK : oV;
        const bool phi = (sel < 2);
        const int ncol0 = col0 & 1023;
        unsigned short* eb = lds + wave * 4096;   // 64 rows x 64 cols bf16
#pragma unroll
        for (int half = 0; half < 2; ++half) {
#pragma unroll
            for (int mf = 0; mf < 4; ++mf) {
                int m = half * 4 + mf;
#pragma unroll
                for (int nf = 0; nf < 4; ++nf)
#pragma unroll
                    for (int r = 0; r < 4; ++r) {
                        float v = acc[m][nf][r];
                        if (phi) v = (v > 0.f) ? (v + 1.f) : __expf(v);
                        eb[(mf * 16 + hi * 4 + r) * 64 + nf * 16 + fr] = f2bf(v);
                    }
            }
            asm volatile("s_waitcnt lgkmcnt(0)" ::: "memory");  // wave-local
#pragma unroll
            for (int rr = 0; rr < 8; ++rr) {
                int row = rr * 8 + (lane >> 3);
                int c8  = (lane & 7) * 8;
                u16x8 vv = *reinterpret_cast<const u16x8*>(eb + row * 64 + c8);
                *reinterpret_cast<u16x8*>(ob + (size_t)(row0 + wm + half * 64 + row) * Dd + ncol0 + wn + c8) = vv;
            }
            asm volatile("s_waitcnt lgkmcnt(0)" ::: "memory");  // reads done before rewrite
        }
    } else {
        float* ebf = reinterpret_cast<float*>(lds) + wave * 2048;  // 32 rows x 64 f32
#pragma unroll
        for (int q = 0; q < 4; ++q) {
#pragma unroll
            for (int mf2 = 0; mf2 < 2; ++mf2) {
                int m = q * 2 + mf2;
#pragma unroll
                for (int nf = 0; nf < 4; ++nf)
#pragma unroll
                    for (int r = 0; r < 4; ++r)
                        ebf[(mf2 * 16 + hi * 4 + r) * 64 + nf * 16 + fr] = acc[m][nf][r];
            }
            asm volatile("s_waitcnt lgkmcnt(0)" ::: "memory");
#pragma unroll
            for (int rr = 0; rr < 8; ++rr) {
                int row = rr * 4 + (lane >> 4);
                int c4  = (lane & 15) * 4;
                float4 vv = *reinterpret_cast<const float4*>(ebf + row * 64 + c4);
                *reinterpret_cast<float4*>(outF + (size_t)(row0 + wm + q * 32 + row) * Dd + col0 + wn + c4) = vv;
            }
            asm volatile("s_waitcnt lgkmcnt(0)" ::: "memory");
        }
    }
}

// ---------------------------------------------------------------------------
// chunk_sums (MFMA): CS'[e][d] = sum_j V[j][e]*K[j][d]  (bf16 out)
//                    CZ[d]     = sum_j K[j][d]          (fp32)
// ---------------------------------------------------------------------------
__global__ __launch_bounds__(256)
void chunk_sums_mfma(const unsigned short* __restrict__ Kb, const unsigned short* __restrict__ Vb,
                     unsigned short* __restrict__ CSb, float* __restrict__ CZ) {
    const int blk = blockIdx.x;
    const int c  = blk & (NCc - 1);
    const int bh = blk >> 5;
    const int b  = bh >> 4;
    const int h  = bh & 15;
    const int tid  = threadIdx.x;
    const int wave = tid >> 6, lane = tid & 63;
    const int lo = lane & 15, hi = lane >> 4;
    const int wr = (wave >> 1) * 32, wc = (wave & 1) * 32;

    __shared__ __align__(16) unsigned short Kt[64][72];
    __shared__ __align__(16) unsigned short Vt[64][72];

    const size_t rowbase = ((size_t)b * SEQ + c * Cc) * Dd + (size_t)h * DHh;

#pragma unroll
    for (int it = 0; it < 2; ++it) {
        int idx = tid + it * 256;
        int r = idx >> 3, c8 = (idx & 7) * 8;
        u16x8 kv = *reinterpret_cast<const u16x8*>(Kb + rowbase + (size_t)r * Dd + c8);
        u16x8 vv = *reinterpret_cast<const u16x8*>(Vb + rowbase + (size_t)r * Dd + c8);
#pragma unroll
        for (int q = 0; q < 8; ++q) {
            int d = c8 + q;
            int sc = swz(d, r);
            Kt[d][sc] = kv[q];
            Vt[d][sc] = vv[q];
        }
    }
    __syncthreads();

    f32x4 acc[2][2];
#pragma unroll
    for (int mf = 0; mf < 2; ++mf)
#pragma unroll
        for (int nf = 0; nf < 2; ++nf) acc[mf][nf] = (f32x4){0.f, 0.f, 0.f, 0.f};

#pragma unroll
    for (int kb = 0; kb < 2; ++kb) {
        const int ko = kb * 32 + hi * 8;
        bf16x8 av[2], bk[2];
#pragma unroll
        for (int mf = 0; mf < 2; ++mf) {
            int row = wr + mf * 16 + lo;
            av[mf] = *reinterpret_cast<const bf16x8*>(&Vt[row][swz(row, ko)]);
        }
#pragma unroll
        for (int nf = 0; nf < 2; ++nf) {
            int row = wc + nf * 16 + lo;
            bk[nf] = *reinterpret_cast<const bf16x8*>(&Kt[row][swz(row, ko)]);
        }
#pragma unroll
        for (int mf = 0; mf < 2; ++mf)
#pragma unroll
            for (int nf = 0; nf < 2; ++nf)
                acc[mf][nf] = __builtin_amdgcn_mfma_f32_16x16x32_bf16(av[mf], bk[nf], acc[mf][nf], 0, 0, 0);
    }

    if (tid < DHh) {
        float s = 0.f;
#pragma unroll
        for (int e8 = 0; e8 < 8; ++e8) {
            u16x8 k8 = *reinterpret_cast<const u16x8*>(&Kt[tid][e8 * 8]);
#pragma unroll
            for (int q = 0; q < 8; ++q) s += bf2f(k8[q]);
        }
        CZ[((size_t)bh * NCc + c) * DHh + tid] = s;
    }

    unsigned short* csb = CSb + ((size_t)bh * NCc + c) * (DHh * DHh);
#pragma unroll
    for (int mf = 0; mf < 2; ++mf)
#pragma unroll
        for (int nf = 0; nf < 2; ++nf)
#pragma unroll
            for (int r = 0; r < 4; ++r) {
                int e = wr + mf * 16 + hi * 4 + r;
                int d = wc + nf * 16 + lo;
                csb[e * DHh + d] = f2bf(acc[mf][nf][r]);
            }
}

// ---------------------------------------------------------------------------
// chunk_scan3: exclusive prefix over 32 chunks, loads up-front into regs.
// ---------------------------------------------------------------------------
__global__ __launch_bounds__(256)
void chunk_scan3(unsigned short* __restrict__ CSb, float* __restrict__ CZ) {
    const int bh = blockIdx.x >> 3;
    const int sl = blockIdx.x & 7;
    const int tid = threadIdx.x;
    const int pos = sl * 512 + tid * 2;
    unsigned* p0 = reinterpret_cast<unsigned*>(CSb + (size_t)bh * NCc * (DHh * DHh) + pos);

    unsigned v[NCc];
#pragma unroll
    for (int c = 0; c < NCc; ++c) v[c] = p0[c * 2048];

    const bool doz = (sl == 0) && (tid < DHh);
    float zv[NCc];
    const size_t zbase = (size_t)bh * NCc * DHh + tid;
    if (doz) {
#pragma unroll
        for (int c = 0; c < NCc; ++c) zv[c] = CZ[zbase + (size_t)c * DHh];
    }

    float a0 = 0.f, a1 = 0.f;
#pragma unroll
    for (int c = 0; c < NCc; ++c) {
        p0[c * 2048] = (unsigned)f2bf(a0) | ((unsigned)f2bf(a1) << 16);
        a0 += bf2f((unsigned short)(v[c] & 0xffff));
        a1 += bf2f((unsigned short)(v[c] >> 16));
    }
    if (doz) {
        float accz = 0.f;
#pragma unroll
        for (int c = 0; c < NCc; ++c) {
            CZ[zbase + (size_t)c * DHh] = accz;
            accz += zv[c];
        }
    }
}

// ---------------------------------------------------------------------------
// chunk_out (MFMA): O = (mask(QK^T)@V + Q@S_prev) / (q.z_prev + rowsum + eps)
// ---------------------------------------------------------------------------
__global__ __launch_bounds__(256)
void chunk_out_mfma(const unsigned short* __restrict__ Qb, const unsigned short* __restrict__ Kb,
                    const unsigned short* __restrict__ Vb, const unsigned short* __restrict__ CSb,
                    const float* __restrict__ CZ, unsigned short* __restrict__ Ob) {
    const int blk = blockIdx.x;
    const int c  = blk & (NCc - 1);
    const int bh = blk >> 5;
    const int b  = bh >> 4;
    const int h  = bh & 15;
    const int tid  = threadIdx.x;
    const int wave = tid >> 6, lane = tid & 63;
    const int lo = lane & 15, hi = lane >> 4;
    const int wr = (wave >> 1) * 32, wc = (wave & 1) * 32;

    __shared__ __align__(16) unsigned short Qs[64][72];
    __shared__ __align__(16) unsigned short KP[64][72];   // K, then P
    __shared__ __align__(16) unsigned short Ss[64][72];   // S_prev' (CS scanned)
    __shared__ __align__(16) unsigned short Vt[64][72];   // V transposed, swizzled
    __shared__ float zsL[DHh];
    __shared__ float rowp[64][2];
    __shared__ float denL[64];

    const size_t rowbase = ((size_t)b * SEQ + c * Cc) * Dd + (size_t)h * DHh;
    const unsigned short* csb = CSb + ((size_t)bh * NCc + c) * (DHh * DHh);

#pragma unroll
    for (int it = 0; it < 2; ++it) {
        int idx = tid + it * 256;
        int r = idx >> 3, c8 = (idx & 7) * 8;
        u16x8 qv = *reinterpret_cast<const u16x8*>(Qb + rowbase + (size_t)r * Dd + c8);
        u16x8 kv = *reinterpret_cast<const u16x8*>(Kb + rowbase + (size_t)r * Dd + c8);
        u16x8 vv = *reinterpret_cast<const u16x8*>(Vb + rowbase + (size_t)r * Dd + c8);
        u16x8 sv = *reinterpret_cast<const u16x8*>(csb + idx * 8);
        *reinterpret_cast<u16x8*>(&Qs[r][c8]) = qv;
        *reinterpret_cast<u16x8*>(&KP[r][c8]) = kv;
        *reinterpret_cast<u16x8*>(&Ss[r][c8]) = sv;
#pragma unroll
        for (int q = 0; q < 8; ++q) {
            int d = c8 + q;
            Vt[d][swz(d, r)] = vv[q];
        }
    }
    if (tid < DHh) zsL[tid] = CZ[((size_t)bh * NCc + c) * DHh + tid];
    __syncthreads();

    f32x4 accs[2][2], accO[2][2];
#pragma unroll
    for (int mf = 0; mf < 2; ++mf)
#pragma unroll
        for (int nf = 0; nf < 2; ++nf) {
            accs[mf][nf] = (f32x4){0.f, 0.f, 0.f, 0.f};
            accO[mf][nf] = (f32x4){0.f, 0.f, 0.f, 0.f};
        }

#pragma unroll
    for (int kb = 0; kb < 2; ++kb) {
        const int ko = kb * 32 + hi * 8;
        bf16x8 aq[2], bk[2], bs[2];
#pragma unroll
        for (int mf = 0; mf < 2; ++mf)
            aq[mf] = *reinterpret_cast<const bf16x8*>(&Qs[wr + mf * 16 + lo][ko]);
#pragma unroll
        for (int nf = 0; nf < 2; ++nf) {
            bk[nf] = *reinterpret_cast<const bf16x8*>(&KP[wc + nf * 16 + lo][ko]);
            bs[nf] = *reinterpret_cast<const bf16x8*>(&Ss[wc + nf * 16 + lo][ko]);
        }
#pragma unroll
        for (int mf = 0; mf < 2; ++mf)
#pragma unroll
            for (int nf = 0; nf < 2; ++nf) {
                accs[mf][nf] = __builtin_amdgcn_mfma_f32_16x16x32_bf16(aq[mf], bk[nf], accs[mf][nf], 0, 0, 0);
                accO[mf][nf] = __builtin_amdgcn_mfma_f32_16x16x32_bf16(aq[mf], bs[nf], accO[mf][nf], 0, 0, 0);
            }
    }

    // mask + rowsum (shfl over the 16-lane lo-group)
#pragma unroll
    for (int mf = 0; mf < 2; ++mf)
#pragma unroll
        for (int r = 0; r < 4; ++r) {
            int i = wr + mf * 16 + hi * 4 + r;
            float s = 0.f;
#pragma unroll
            for (int nf = 0; nf < 2; ++nf) {
                int j = wc + nf * 16 + lo;
                float v = (j <= i) ? accs[mf][nf][r] : 0.f;
                accs[mf][nf][r] = v;
                s += v;
            }
            s += __shfl_xor(s, 1); s += __shfl_xor(s, 2);
            s += __shfl_xor(s, 4); s += __shfl_xor(s, 8);
            if (lo == 0) rowp[i][wave & 1] = s;
        }
    __syncthreads();

    // P (bf16) -> KP buffer; den on 64 threads
#pragma unroll
    for (int mf = 0; mf < 2; ++mf)
#pragma unroll
        for (int nf = 0; nf < 2; ++nf)
#pragma unroll
            for (int r = 0; r < 4; ++r)
                KP[wr + mf * 16 + hi * 4 + r][wc + nf * 16 + lo] = f2bf(accs[mf][nf][r]);
    if (tid < 64) {
        float d = 0.f;
#pragma unroll
        for (int e8 = 0; e8 < 8; ++e8) {
            u16x8 q8 = *reinterpret_cast<const u16x8*>(&Qs[tid][e8 * 8]);
#pragma unroll
            for (int q = 0; q < 8; ++q) d += bf2f(q8[q]) * zsL[e8 * 8 + q];
        }
        denL[tid] = d + rowp[tid][0] + rowp[tid][1] + EPSf;
    }
    __syncthreads();

    // intra: accO += P V
#pragma unroll
    for (int kb = 0; kb < 2; ++kb) {
        const int ko = kb * 32 + hi * 8;
        bf16x8 ap[2], bv[2];
#pragma unroll
        for (int mf = 0; mf < 2; ++mf)
            ap[mf] = *reinterpret_cast<const bf16x8*>(&KP[wr + mf * 16 + lo][ko]);
#pragma unroll
        for (int nf = 0; nf < 2; ++nf) {
            int row = wc + nf * 16 + lo;
            bv[nf] = *reinterpret_cast<const bf16x8*>(&Vt[row][swz(row, ko)]);
        }
#pragma unroll
        for (int mf = 0; mf < 2; ++mf)
#pragma unroll
            for (int nf = 0; nf < 2; ++nf)
                accO[mf][nf] = __builtin_amdgcn_mfma_f32_16x16x32_bf16(ap[mf], bv[nf], accO[mf][nf], 0, 0, 0);
    }

    // epilogue
#pragma unroll
    for (int mf = 0; mf < 2; ++mf)
#pragma unroll
        for (int r = 0; r < 4; ++r) {
            int i = wr + mf * 16 + hi * 4 + r;
            float inv = 1.0f / denL[i];
#pragma unroll
            for (int nf = 0; nf < 2; ++nf) {
                int e = wc + nf * 16 + lo;
                Ob[rowbase + (size_t)i * Dd + e] = f2bf(accO[mf][nf][r] * inv);
            }
        }
}

// ---------------------------------------------------------------------------
extern "C" void kernel_launch(void* const* d_in, const int* in_sizes, int n_in,
                              void* d_out, int out_size, void* d_ws, size_t ws_size,
                              hipStream_t stream) {
    const float* x  = (const float*)d_in[0];
    const float* Wq = (const float*)d_in[1];
    const float* Wk = (const float*)d_in[2];
    const float* Wv = (const float*)d_in[3];
    const float* Wo = (const float*)d_in[4];

    const size_t NMD = (size_t)Mm * Dd;       // 8388608
    const size_t NW  = (size_t)Dd * Dd;       // 1048576
    unsigned short* xb  = (unsigned short*)d_ws;           // 16 MB
    unsigned short* WT  = xb + NMD;                        // 8 MB (Wq^T|Wk^T|Wv^T|Wo^T)
    unsigned short* Qb  = WT + 4 * NW;                     // 16 MB
    unsigned short* Kb  = Qb + NMD;                        // 16 MB
    unsigned short* Vb  = Kb + NMD;                        // 16 MB
    unsigned short* Obf = Vb + NMD;                        // 16 MB
    unsigned short* CSb = Obf + NMD;                       // 16.8 MB (bf16, scanned in-place)
    float* CZ = (float*)(CSb + (size_t)Bb * Hh * NCc * DHh * DHh); // 0.5 MB

    // fused cast + weight transpose
    prep<<<4096 + 1024, 256, 0, stream>>>(x, Wq, Wk, Wv, Wo, xb, WT);

    // fused QKV projection: N=3072 over contiguous (Wq^T|Wk^T|Wv^T); phi on Q,K
    gemm_256s<1><<<12 * 32, 512, 0, stream>>>(xb, WT, nullptr, Qb, Kb, Vb);

    // chunked linear attention (MFMA)
    chunk_sums_mfma<<<Bb * Hh * NCc, 256, 0, stream>>>(Kb, Vb, CSb, CZ);
    chunk_scan3<<<Bb * Hh * 8, 256, 0, stream>>>(CSb, CZ);
    chunk_out_mfma<<<Bb * Hh * NCc, 256, 0, stream>>>(Qb, Kb, Vb, CSb, CZ, Obf);

    // output projection -> d_out (fp32)
    gemm_256s<0><<<4 * 32, 512, 0, stream>>>(Obf, WT + 3 * NW, (float*)d_out, nullptr, nullptr, nullptr);
}

// Round 13
// 123.901 us; speedup vs baseline: 9.3099x; 9.3099x over previous
//
#include <hip/hip_runtime.h>
#include <hip/hip_bf16.h>
#include <math.h>

// Problem constants
constexpr int Bb  = 4;
constexpr int SEQ = 2048;
constexpr int Dd  = 1024;
constexpr int Hh  = 16;
constexpr int DHh = 64;
constexpr int Cc  = 64;            // chunk length
constexpr int NCc = SEQ / Cc;      // 32 chunks
constexpr int Mm  = Bb * SEQ;      // 8192 rows
constexpr float EPSf = 1e-6f;

typedef __attribute__((ext_vector_type(8))) short bf16x8;
typedef __attribute__((ext_vector_type(4))) float f32x4;
typedef __attribute__((ext_vector_type(8))) unsigned short u16x8;

__device__ __forceinline__ float bf2f(unsigned short u) {
    return __uint_as_float((unsigned)u << 16);
}
__device__ __forceinline__ unsigned short f2bf(float f) {
    unsigned u = __float_as_uint(f);
    unsigned r = u + 0x7fff + ((u >> 16) & 1);   // RNE
    return (unsigned short)(r >> 16);
}
// XOR swizzle for transposed LDS tiles (chunk kernels)
__device__ __forceinline__ int swz(int row, int col) {
    return col ^ (((row >> 3) & 7) << 3);
}

// ---------------------------------------------------------------------------
// prep: fused {x fp32->bf16 cast} + {W transpose-cast}.
// ---------------------------------------------------------------------------
__global__ __launch_bounds__(256)
void prep(const float* __restrict__ x,
          const float* __restrict__ W0, const float* __restrict__ W1,
          const float* __restrict__ W2, const float* __restrict__ W3,
          unsigned short* __restrict__ xb, unsigned short* __restrict__ WT) {
    __shared__ float t[64][65];
    const int tid = threadIdx.x;
    if (blockIdx.x < 4096) {
        int i = blockIdx.x * 256 + tid;
        const float4* p = reinterpret_cast<const float4*>(x) + (size_t)i * 2;
        float4 a = p[0], b = p[1];
        u16x8 o;
        o[0] = f2bf(a.x); o[1] = f2bf(a.y); o[2] = f2bf(a.z); o[3] = f2bf(a.w);
        o[4] = f2bf(b.x); o[5] = f2bf(b.y); o[6] = f2bf(b.z); o[7] = f2bf(b.w);
        *(reinterpret_cast<u16x8*>(xb) + i) = o;
        return;
    }
    const int tb = blockIdx.x - 4096;
    const int z  = tb >> 8;
    const int by = (tb >> 4) & 15, bx = tb & 15;
    const float* W = (z == 0) ? W0 : (z == 1) ? W1 : (z == 2) ? W2 : W3;
    unsigned short* T = WT + (size_t)z * Dd * Dd;
    const int r0 = by * 64, c0 = bx * 64;
    const int lr = tid >> 4, lc4 = (tid & 15) * 4;
#pragma unroll
    for (int it = 0; it < 4; ++it) {
        int row = lr + it * 16;
        float4 v = *reinterpret_cast<const float4*>(W + (size_t)(r0 + row) * Dd + c0 + lc4);
        t[row][lc4 + 0] = v.x; t[row][lc4 + 1] = v.y;
        t[row][lc4 + 2] = v.z; t[row][lc4 + 3] = v.w;
    }
    __syncthreads();
#pragma unroll
    for (int it = 0; it < 4; ++it) {
        int col = lr + it * 16;
        ushort4 o;
        o.x = f2bf(t[lc4 + 0][col]); o.y = f2bf(t[lc4 + 1][col]);
        o.z = f2bf(t[lc4 + 2][col]); o.w = f2bf(t[lc4 + 3][col]);
        *reinterpret_cast<ushort4*>(T + (size_t)(c0 + col) * Dd + r0 + lc4) = o;
    }
}

// ---------------------------------------------------------------------------
// bf16 MFMA GEMM — round-7 measured-best K-loop (QKV 61.2us / out ~19.5us):
//   BM=128, BN=256, BK=64; 512 threads = 8 waves (2M x 4N), wave 64x64.
//   Triple-buffered LDS (144 KB), 2-deep prefetch, counted vmcnt(6).
//   ONE barrier per K-tile; 4 MFMA groups of 8 with counted lgkmcnt waits.
//   XCD A-band mapping (by = xcd*8 + i/GX): A-band 2MB L2-resident per XCD.
//   Vectorized epilogue via wave-private LDS regions.
// NOTE (round-12 lesson): wave tiles needing >128 VGPR cannot coexist with
// 2 blocks/CU at 512 threads — check {VGPR, LDS, waves} jointly.
// QKV=1: N=3072 fused (Wq|Wk|Wv), bf16 out, phi on Q,K. QKV=0: N=1024, f32.
// ---------------------------------------------------------------------------
template<int QKV>
__global__ __launch_bounds__(512, 1)
void gemm_pipe(const unsigned short* __restrict__ A, const unsigned short* __restrict__ BT,
               float* __restrict__ outF, unsigned short* __restrict__ oQ,
               unsigned short* __restrict__ oK, unsigned short* __restrict__ oV) {
    constexpr int Kd  = 1024;
    constexpr int BK  = 64;
    constexpr int NT  = Kd / BK;           // 16 K-tiles
    constexpr int GX  = QKV ? 12 : 4;      // N / 256
    constexpr int BUFSZ = (128 + 256) * BK;   // elems per buffer (A 8192 + B 16384)

    __shared__ __align__(16) unsigned short lds[3 * BUFSZ];   // 144 KB

    // XCD A-band mapping (bijective; consecutive blockIdx round-robin XCDs)
    const int wg0 = blockIdx.x;
    const int xcd = wg0 & 7;
    const int i   = wg0 >> 3;              // 0 .. NWG/8-1  (NWG/8 = 8*GX)
    const int by  = xcd * 8 + i / GX;      // 8 row-blocks per XCD: A-band 2 MB
    const int bx  = i % GX;
    const int row0 = by * 128;
    const int col0 = bx * 256;

    const int tid  = threadIdx.x;
    const int lane = tid & 63;
    const int wave = tid >> 6;
    const int wm = (wave >> 2) * 64;       // wave M offset (0,64)
    const int wn = (wave & 3) * 64;        // wave N offset (0..192)
    const int fr = lane & 15;
    const int hi = lane >> 4;

    f32x4 acc[4][4];
#pragma unroll
    for (int mf = 0; mf < 4; ++mf)
#pragma unroll
        for (int nf = 0; nf < 4; ++nf) acc[mf][nf] = (f32x4){0.f, 0.f, 0.f, 0.f};

    // one 16B staging load; l in 0..5 (literal at every call site)
    auto stage1 = [&](int sel, int kt, int l) {
        unsigned short* base = &lds[sel * BUFSZ];
        int seg = l * 512 + tid;                      // 0..3071
        if (l < 2) {                                  // A: segs 0..1023
            int row = seg >> 3, sp = seg & 7;
            int gcol = kt + ((sp ^ (row & 7)) << 3);  // inverse-swizzled source
            __builtin_amdgcn_global_load_lds(
                (const __attribute__((address_space(1))) void*)(A + (size_t)(row0 + row) * Kd + gcol),
                (__attribute__((address_space(3))) void*)(base + seg * 8), 16, 0, 0);
        } else {                                      // B: segs 0..2047
            int bseg = seg - 1024;
            int row = bseg >> 3, sp = bseg & 7;
            int gcol = kt + ((sp ^ (row & 7)) << 3);
            __builtin_amdgcn_global_load_lds(
                (const __attribute__((address_space(1))) void*)(BT + (size_t)(col0 + row) * Kd + gcol),
                (__attribute__((address_space(3))) void*)(base + 8192 + bseg * 8), 16, 0, 0);
        }
    };
    // swizzled fragment reads (row multiple of 16 => row&7 == fr&7)
    auto lda = [&](const unsigned short* bufA, int mf, int ks) {
        int row = wm + mf * 16 + fr;
        int sp = ((ks << 2) | hi) ^ (row & 7);
        return *reinterpret_cast<const bf16x8*>(bufA + row * 64 + sp * 8);
    };
    auto ldb = [&](const unsigned short* bufB, int nf, int ks) {
        int row = wn + nf * 16 + fr;
        int sp = ((ks << 2) | hi) ^ (row & 7);
        return *reinterpret_cast<const bf16x8*>(bufB + row * 64 + sp * 8);
    };

    // prologue: stage tiles 0 and 1
#pragma unroll
    for (int l = 0; l < 6; ++l) stage1(0, 0, l);
#pragma unroll
    for (int l = 0; l < 6; ++l) stage1(1, BK, l);

    int selc = 0;
    for (int t = 0; t < NT; ++t) {
        // drain tile t's 6 stage loads, keep tile t+1's 6 in flight
        if (t < NT - 1) { asm volatile("s_waitcnt vmcnt(6)" ::: "memory"); }
        else            { asm volatile("s_waitcnt vmcnt(0)" ::: "memory"); }
        __builtin_amdgcn_sched_barrier(0);
        __builtin_amdgcn_s_barrier();        // ONE barrier per K-tile
        __builtin_amdgcn_sched_barrier(0);

        const unsigned short* bufA = &lds[selc * BUFSZ];
        const unsigned short* bufB = bufA + 8192;
        int sels = selc + 2; if (sels >= 3) sels -= 3;
        const bool st = (t + 2 < NT);
        const int kt2 = (t + 2) * BK;

        bf16x8 a0_[4], a1_[4], bL[2], bM[2], bN[2], bO[2];

        // R0 (6) + R1 (2): 8 outstanding
#pragma unroll
        for (int mf = 0; mf < 4; ++mf) a0_[mf] = lda(bufA, mf, 0);
        bL[0] = ldb(bufB, 0, 0); bL[1] = ldb(bufB, 1, 0);
        bM[0] = ldb(bufB, 2, 0); bM[1] = ldb(bufB, 3, 0);

        // wait R0 done (6 oldest) -> G0
        asm volatile("s_waitcnt lgkmcnt(2)" ::: "memory");
        __builtin_amdgcn_sched_barrier(0);
        __builtin_amdgcn_s_setprio(1);
#pragma unroll
        for (int mf = 0; mf < 4; ++mf) {
            acc[mf][0] = __builtin_amdgcn_mfma_f32_16x16x32_bf16(a0_[mf], bL[0], acc[mf][0], 0, 0, 0);
            acc[mf][1] = __builtin_amdgcn_mfma_f32_16x16x32_bf16(a0_[mf], bL[1], acc[mf][1], 0, 0, 0);
        }
        __builtin_amdgcn_s_setprio(0);

        // R2 (6) under G0's shadow; stage 3
#pragma unroll
        for (int mf = 0; mf < 4; ++mf) a1_[mf] = lda(bufA, mf, 1);
        bN[0] = ldb(bufB, 0, 1); bN[1] = ldb(bufB, 1, 1);
        if (st) { stage1(sels, kt2, 0); stage1(sels, kt2, 1); stage1(sels, kt2, 2); }

        // wait R1 (bM) done -> G1
        asm volatile("s_waitcnt lgkmcnt(6)" ::: "memory");
        __builtin_amdgcn_sched_barrier(0);
        __builtin_amdgcn_s_setprio(1);
#pragma unroll
        for (int mf = 0; mf < 4; ++mf) {
            acc[mf][2] = __builtin_amdgcn_mfma_f32_16x16x32_bf16(a0_[mf], bM[0], acc[mf][2], 0, 0, 0);
            acc[mf][3] = __builtin_amdgcn_mfma_f32_16x16x32_bf16(a0_[mf], bM[1], acc[mf][3], 0, 0, 0);
        }
        __builtin_amdgcn_s_setprio(0);

        // R3 (2); stage 3
        bO[0] = ldb(bufB, 2, 1); bO[1] = ldb(bufB, 3, 1);
        if (st) { stage1(sels, kt2, 3); stage1(sels, kt2, 4); stage1(sels, kt2, 5); }

        // wait R2 (a1,bN) done -> G2
        asm volatile("s_waitcnt lgkmcnt(2)" ::: "memory");
        __builtin_amdgcn_sched_barrier(0);
        __builtin_amdgcn_s_setprio(1);
#pragma unroll
        for (int mf = 0; mf < 4; ++mf) {
            acc[mf][0] = __builtin_amdgcn_mfma_f32_16x16x32_bf16(a1_[mf], bN[0], acc[mf][0], 0, 0, 0);
            acc[mf][1] = __builtin_amdgcn_mfma_f32_16x16x32_bf16(a1_[mf], bN[1], acc[mf][1], 0, 0, 0);
        }
        __builtin_amdgcn_s_setprio(0);

        // wait R3 (bO) done -> G3 (all reads of this buffer complete here)
        asm volatile("s_waitcnt lgkmcnt(0)" ::: "memory");
        __builtin_amdgcn_sched_barrier(0);
        __builtin_amdgcn_s_setprio(1);
#pragma unroll
        for (int mf = 0; mf < 4; ++mf) {
            acc[mf][2] = __builtin_amdgcn_mfma_f32_16x16x32_bf16(a1_[mf], bO[0], acc[mf][2], 0, 0, 0);
            acc[mf][3] = __builtin_amdgcn_mfma_f32_16x16x32_bf16(a1_[mf], bO[1], acc[mf][3], 0, 0, 0);
        }
        __builtin_amdgcn_s_setprio(0);

        selc = (selc == 2) ? 0 : selc + 1;
    }

    // ---- vectorized epilogue via wave-private LDS regions ----
    __syncthreads();                       // all K-loop LDS reads complete

    if (QKV) {
        const int sel = col0 >> 10;        // 0=Q,1=K,2=V
        unsigned short* ob = (sel == 0) ? oQ : (sel == 1) ? oK : oV;
        const bool phi = (sel < 2);
        const int ncol0 = col0 & 1023;
        unsigned short* eb = lds + wave * 4096;   // 8 KB/wave, 64 KB total
#pragma unroll
        for (int mf = 0; mf < 4; ++mf)
#pragma unroll
            for (int nf = 0; nf < 4; ++nf)
#pragma unroll
                for (int r = 0; r < 4; ++r) {
                    float v = acc[mf][nf][r];
                    if (phi) v = (v > 0.f) ? (v + 1.f) : __expf(v);
                    eb[(mf * 16 + hi * 4 + r) * 64 + nf * 16 + fr] = f2bf(v);
                }
        asm volatile("s_waitcnt lgkmcnt(0)" ::: "memory");   // wave-local writes done
#pragma unroll
        for (int rr = 0; rr < 8; ++rr) {
            int row = rr * 8 + (lane >> 3);
            int c8  = (lane & 7) * 8;
            u16x8 vv = *reinterpret_cast<const u16x8*>(eb + row * 64 + c8);
            *reinterpret_cast<u16x8*>(ob + (size_t)(row0 + wm + row) * Dd + ncol0 + wn + c8) = vv;
        }
    } else {
        float* ebf = reinterpret_cast<float*>(lds) + wave * 4096;   // 16 KB/wave, 128 KB
#pragma unroll
        for (int mf = 0; mf < 4; ++mf)
#pragma unroll
            for (int nf = 0; nf < 4; ++nf)
#pragma unroll
                for (int r = 0; r < 4; ++r)
                    ebf[(mf * 16 + hi * 4 + r) * 64 + nf * 16 + fr] = acc[mf][nf][r];
        asm volatile("s_waitcnt lgkmcnt(0)" ::: "memory");
#pragma unroll
        for (int rr = 0; rr < 16; ++rr) {
            int row = rr * 4 + (lane >> 4);
            int c4  = (lane & 15) * 4;
            float4 vv = *reinterpret_cast<const float4*>(ebf + row * 64 + c4);
            *reinterpret_cast<float4*>(outF + (size_t)(row0 + wm + row) * Dd + col0 + wn + c4) = vv;
        }
    }
}

// ---------------------------------------------------------------------------
// chunk_sums (MFMA): CS'[e][d] = sum_j V[j][e]*K[j][d]  (bf16 out)
//                    CZ[d]     = sum_j K[j][d]          (fp32)
// ---------------------------------------------------------------------------
__global__ __launch_bounds__(256)
void chunk_sums_mfma(const unsigned short* __restrict__ Kb, const unsigned short* __restrict__ Vb,
                     unsigned short* __restrict__ CSb, float* __restrict__ CZ) {
    const int blk = blockIdx.x;
    const int c  = blk & (NCc - 1);
    const int bh = blk >> 5;
    const int b  = bh >> 4;
    const int h  = bh & 15;
    const int tid  = threadIdx.x;
    const int wave = tid >> 6, lane = tid & 63;
    const int lo = lane & 15, hi = lane >> 4;
    const int wr = (wave >> 1) * 32, wc = (wave & 1) * 32;

    __shared__ __align__(16) unsigned short Kt[64][72];
    __shared__ __align__(16) unsigned short Vt[64][72];

    const size_t rowbase = ((size_t)b * SEQ + c * Cc) * Dd + (size_t)h * DHh;

#pragma unroll
    for (int it = 0; it < 2; ++it) {
        int idx = tid + it * 256;
        int r = idx >> 3, c8 = (idx & 7) * 8;
        u16x8 kv = *reinterpret_cast<const u16x8*>(Kb + rowbase + (size_t)r * Dd + c8);
        u16x8 vv = *reinterpret_cast<const u16x8*>(Vb + rowbase + (size_t)r * Dd + c8);
#pragma unroll
        for (int q = 0; q < 8; ++q) {
            int d = c8 + q;
            int sc = swz(d, r);
            Kt[d][sc] = kv[q];
            Vt[d][sc] = vv[q];
        }
    }
    __syncthreads();

    f32x4 acc[2][2];
#pragma unroll
    for (int mf = 0; mf < 2; ++mf)
#pragma unroll
        for (int nf = 0; nf < 2; ++nf) acc[mf][nf] = (f32x4){0.f, 0.f, 0.f, 0.f};

#pragma unroll
    for (int kb = 0; kb < 2; ++kb) {
        const int ko = kb * 32 + hi * 8;
        bf16x8 av[2], bk[2];
#pragma unroll
        for (int mf = 0; mf < 2; ++mf) {
            int row = wr + mf * 16 + lo;
            av[mf] = *reinterpret_cast<const bf16x8*>(&Vt[row][swz(row, ko)]);
        }
#pragma unroll
        for (int nf = 0; nf < 2; ++nf) {
            int row = wc + nf * 16 + lo;
            bk[nf] = *reinterpret_cast<const bf16x8*>(&Kt[row][swz(row, ko)]);
        }
#pragma unroll
        for (int mf = 0; mf < 2; ++mf)
#pragma unroll
            for (int nf = 0; nf < 2; ++nf)
                acc[mf][nf] = __builtin_amdgcn_mfma_f32_16x16x32_bf16(av[mf], bk[nf], acc[mf][nf], 0, 0, 0);
    }

    if (tid < DHh) {
        float s = 0.f;
#pragma unroll
        for (int e8 = 0; e8 < 8; ++e8) {
            u16x8 k8 = *reinterpret_cast<const u16x8*>(&Kt[tid][e8 * 8]);
#pragma unroll
            for (int q = 0; q < 8; ++q) s += bf2f(k8[q]);
        }
        CZ[((size_t)bh * NCc + c) * DHh + tid] = s;
    }

    unsigned short* csb = CSb + ((size_t)bh * NCc + c) * (DHh * DHh);
#pragma unroll
    for (int mf = 0; mf < 2; ++mf)
#pragma unroll
        for (int nf = 0; nf < 2; ++nf)
#pragma unroll
            for (int r = 0; r < 4; ++r) {
                int e = wr + mf * 16 + hi * 4 + r;
                int d = wc + nf * 16 + lo;
                csb[e * DHh + d] = f2bf(acc[mf][nf][r]);
            }
}

// ---------------------------------------------------------------------------
// chunk_scan3: exclusive prefix over 32 chunks, loads up-front into regs.
// ---------------------------------------------------------------------------
__global__ __launch_bounds__(256)
void chunk_scan3(unsigned short* __restrict__ CSb, float* __restrict__ CZ) {
    const int bh = blockIdx.x >> 3;
    const int sl = blockIdx.x & 7;
    const int tid = threadIdx.x;
    const int pos = sl * 512 + tid * 2;
    unsigned* p0 = reinterpret_cast<unsigned*>(CSb + (size_t)bh * NCc * (DHh * DHh) + pos);

    unsigned v[NCc];
#pragma unroll
    for (int c = 0; c < NCc; ++c) v[c] = p0[c * 2048];

    const bool doz = (sl == 0) && (tid < DHh);
    float zv[NCc];
    const size_t zbase = (size_t)bh * NCc * DHh + tid;
    if (doz) {
#pragma unroll
        for (int c = 0; c < NCc; ++c) zv[c] = CZ[zbase + (size_t)c * DHh];
    }

    float a0 = 0.f, a1 = 0.f;
#pragma unroll
    for (int c = 0; c < NCc; ++c) {
        p0[c * 2048] = (unsigned)f2bf(a0) | ((unsigned)f2bf(a1) << 16);
        a0 += bf2f((unsigned short)(v[c] & 0xffff));
        a1 += bf2f((unsigned short)(v[c] >> 16));
    }
    if (doz) {
        float accz = 0.f;
#pragma unroll
        for (int c = 0; c < NCc; ++c) {
            CZ[zbase + (size_t)c * DHh] = accz;
            accz += zv[c];
        }
    }
}

// ---------------------------------------------------------------------------
// chunk_out (MFMA): O = (mask(QK^T)@V + Q@S_prev) / (q.z_prev + rowsum + eps)
// ---------------------------------------------------------------------------
__global__ __launch_bounds__(256)
void chunk_out_mfma(const unsigned short* __restrict__ Qb, const unsigned short* __restrict__ Kb,
                    const unsigned short* __restrict__ Vb, const unsigned short* __restrict__ CSb,
                    const float* __restrict__ CZ, unsigned short* __restrict__ Ob) {
    const int blk = blockIdx.x;
    const int c  = blk & (NCc - 1);
    const int bh = blk >> 5;
    const int b  = bh >> 4;
    const int h  = bh & 15;
    const int tid  = threadIdx.x;
    const int wave = tid >> 6, lane = tid & 63;
    const int lo = lane & 15, hi = lane >> 4;
    const int wr = (wave >> 1) * 32, wc = (wave & 1) * 32;

    __shared__ __align__(16) unsigned short Qs[64][72];
    __shared__ __align__(16) unsigned short KP[64][72];   // K, then P
    __shared__ __align__(16) unsigned short Ss[64][72];   // S_prev' (CS scanned)
    __shared__ __align__(16) unsigned short Vt[64][72];   // V transposed, swizzled
    __shared__ float zsL[DHh];
    __shared__ float rowp[64][2];
    __shared__ float denL[64];

    const size_t rowbase = ((size_t)b * SEQ + c * Cc) * Dd + (size_t)h * DHh;
    const unsigned short* csb = CSb + ((size_t)bh * NCc + c) * (DHh * DHh);

#pragma unroll
    for (int it = 0; it < 2; ++it) {
        int idx = tid + it * 256;
        int r = idx >> 3, c8 = (idx & 7) * 8;
        u16x8 qv = *reinterpret_cast<const u16x8*>(Qb + rowbase + (size_t)r * Dd + c8);
        u16x8 kv = *reinterpret_cast<const u16x8*>(Kb + rowbase + (size_t)r * Dd + c8);
        u16x8 vv = *reinterpret_cast<const u16x8*>(Vb + rowbase + (size_t)r * Dd + c8);
        u16x8 sv = *reinterpret_cast<const u16x8*>(csb + idx * 8);
        *reinterpret_cast<u16x8*>(&Qs[r][c8]) = qv;
        *reinterpret_cast<u16x8*>(&KP[r][c8]) = kv;
        *reinterpret_cast<u16x8*>(&Ss[r][c8]) = sv;
#pragma unroll
        for (int q = 0; q < 8; ++q) {
            int d = c8 + q;
            Vt[d][swz(d, r)] = vv[q];
        }
    }
    if (tid < DHh) zsL[tid] = CZ[((size_t)bh * NCc + c) * DHh + tid];
    __syncthreads();

    f32x4 accs[2][2], accO[2][2];
#pragma unroll
    for (int mf = 0; mf < 2; ++mf)
#pragma unroll
        for (int nf = 0; nf < 2; ++nf) {
            accs[mf][nf] = (f32x4){0.f, 0.f, 0.f, 0.f};
            accO[mf][nf] = (f32x4){0.f, 0.f, 0.f, 0.f};
        }

#pragma unroll
    for (int kb = 0; kb < 2; ++kb) {
        const int ko = kb * 32 + hi * 8;
        bf16x8 aq[2], bk[2], bs[2];
#pragma unroll
        for (int mf = 0; mf < 2; ++mf)
            aq[mf] = *reinterpret_cast<const bf16x8*>(&Qs[wr + mf * 16 + lo][ko]);
#pragma unroll
        for (int nf = 0; nf < 2; ++nf) {
            bk[nf] = *reinterpret_cast<const bf16x8*>(&KP[wc + nf * 16 + lo][ko]);
            bs[nf] = *reinterpret_cast<const bf16x8*>(&Ss[wc + nf * 16 + lo][ko]);
        }
#pragma unroll
        for (int mf = 0; mf < 2; ++mf)
#pragma unroll
            for (int nf = 0; nf < 2; ++nf) {
                accs[mf][nf] = __builtin_amdgcn_mfma_f32_16x16x32_bf16(aq[mf], bk[nf], accs[mf][nf], 0, 0, 0);
                accO[mf][nf] = __builtin_amdgcn_mfma_f32_16x16x32_bf16(aq[mf], bs[nf], accO[mf][nf], 0, 0, 0);
            }
    }

    // mask + rowsum (shfl over the 16-lane lo-group)
#pragma unroll
    for (int mf = 0; mf < 2; ++mf)
#pragma unroll
        for (int r = 0; r < 4; ++r) {
            int i = wr + mf * 16 + hi * 4 + r;
            float s = 0.f;
#pragma unroll
            for (int nf = 0; nf < 2; ++nf) {
                int j = wc + nf * 16 + lo;
                float v = (j <= i) ? accs[mf][nf][r] : 0.f;
                accs[mf][nf][r] = v;
                s += v;
            }
            s += __shfl_xor(s, 1); s += __shfl_xor(s, 2);
            s += __shfl_xor(s, 4); s += __shfl_xor(s, 8);
            if (lo == 0) rowp[i][wave & 1] = s;
        }
    __syncthreads();

    // P (bf16) -> KP buffer; den on 64 threads
#pragma unroll
    for (int mf = 0; mf < 2; ++mf)
#pragma unroll
        for (int nf = 0; nf < 2; ++nf)
#pragma unroll
            for (int r = 0; r < 4; ++r)
                KP[wr + mf * 16 + hi * 4 + r][wc + nf * 16 + lo] = f2bf(accs[mf][nf][r]);
    if (tid < 64) {
        float d = 0.f;
#pragma unroll
        for (int e8 = 0; e8 < 8; ++e8) {
            u16x8 q8 = *reinterpret_cast<const u16x8*>(&Qs[tid][e8 * 8]);
#pragma unroll
            for (int q = 0; q < 8; ++q) d += bf2f(q8[q]) * zsL[e8 * 8 + q];
        }
        denL[tid] = d + rowp[tid][0] + rowp[tid][1] + EPSf;
    }
    __syncthreads();

    // intra: accO += P V
#pragma unroll
    for (int kb = 0; kb < 2; ++kb) {
        const int ko = kb * 32 + hi * 8;
        bf16x8 ap[2], bv[2];
#pragma unroll
        for (int mf = 0; mf < 2; ++mf)
            ap[mf] = *reinterpret_cast<const bf16x8*>(&KP[wr + mf * 16 + lo][ko]);
#pragma unroll
        for (int nf = 0; nf < 2; ++nf) {
            int row = wc + nf * 16 + lo;
            bv[nf] = *reinterpret_cast<const bf16x8*>(&Vt[row][swz(row, ko)]);
        }
#pragma unroll
        for (int mf = 0; mf < 2; ++mf)
#pragma unroll
            for (int nf = 0; nf < 2; ++nf)
                accO[mf][nf] = __builtin_amdgcn_mfma_f32_16x16x32_bf16(ap[mf], bv[nf], accO[mf][nf], 0, 0, 0);
    }

    // epilogue
#pragma unroll
    for (int mf = 0; mf < 2; ++mf)
#pragma unroll
        for (int r = 0; r < 4; ++r) {
            int i = wr + mf * 16 + hi * 4 + r;
            float inv = 1.0f / denL[i];
#pragma unroll
            for (int nf = 0; nf < 2; ++nf) {
                int e = wc + nf * 16 + lo;
                Ob[rowbase + (size_t)i * Dd + e] = f2bf(accO[mf][nf][r] * inv);
            }
        }
}

// ---------------------------------------------------------------------------
extern "C" void kernel_launch(void* const* d_in, const int* in_sizes, int n_in,
                              void* d_out, int out_size, void* d_ws, size_t ws_size,
                              hipStream_t stream) {
    const float* x  = (const float*)d_in[0];
    const float* Wq = (const float*)d_in[1];
    const float* Wk = (const float*)d_in[2];
    const float* Wv = (const float*)d_in[3];
    const float* Wo = (const float*)d_in[4];

    const size_t NMD = (size_t)Mm * Dd;       // 8388608
    const size_t NW  = (size_t)Dd * Dd;       // 1048576
    unsigned short* xb  = (unsigned short*)d_ws;           // 16 MB
    unsigned short* WT  = xb + NMD;                        // 8 MB (Wq^T|Wk^T|Wv^T|Wo^T)
    unsigned short* Qb  = WT + 4 * NW;                     // 16 MB
    unsigned short* Kb  = Qb + NMD;                        // 16 MB
    unsigned short* Vb  = Kb + NMD;                        // 16 MB
    unsigned short* Obf = Vb + NMD;                        // 16 MB
    unsigned short* CSb = Obf + NMD;                       // 16.8 MB (bf16, scanned in-place)
    float* CZ = (float*)(CSb + (size_t)Bb * Hh * NCc * DHh * DHh); // 0.5 MB

    // fused cast + weight transpose
    prep<<<4096 + 1024, 256, 0, stream>>>(x, Wq, Wk, Wv, Wo, xb, WT);

    // fused QKV projection: N=3072 over contiguous (Wq^T|Wk^T|Wv^T); phi on Q,K
    gemm_pipe<1><<<12 * 64, 512, 0, stream>>>(xb, WT, nullptr, Qb, Kb, Vb);

    // chunked linear attention (MFMA)
    chunk_sums_mfma<<<Bb * Hh * NCc, 256, 0, stream>>>(Kb, Vb, CSb, CZ);
    chunk_scan3<<<Bb * Hh * 8, 256, 0, stream>>>(CSb, CZ);
    chunk_out_mfma<<<Bb * Hh * NCc, 256, 0, stream>>>(Qb, Kb, Vb, CSb, CZ, Obf);

    // output projection -> d_out (fp32)
    gemm_pipe<0><<<4 * 64, 512, 0, stream>>>(Obf, WT + 3 * NW, (float*)d_out, nullptr, nullptr, nullptr);
}